// Round 3
// baseline (91.900 us; speedup 1.0000x reference)
//
#include <hip/hip_runtime.h>

// Problem constants (fixed by the reference setup)
#define B_ 128
#define N_ 65536
#define P_ 4096
#define T_ 32
#define D_ 2
#define K_ 4
#define S_ 16                      // slices per batch
#define PPB 256                    // pairs per block (P_/S_)

// sorted-descending top-4 insert chain (7 ops)
#define INS(v0, v1, v2, v3, val)                                  \
    {                                                             \
        float _x = fminf(v0, val); v0 = fmaxf(v0, val);           \
        float _y = fminf(v1, _x);  v1 = fmaxf(v1, _x);            \
        float _z = fminf(v2, _y);  v2 = fmaxf(v2, _y);            \
        v3 = fmaxf(v3, _z);                                       \
    }

// ---------------------------------------------------------------------------
// Fused kernel: each block owns (batch, slice) = 256 pairs, 1 pair/thread.
//  grid = 2048 blocks -> 8 blocks/CU co-resident (launch_bounds caps VGPR=64)
//  so gather latency (idx HBM load -> random L2 fun read) is covered by TLP.
//  1. gather b/d from fun (XCD-swizzled: one batch's 16 slices on one XCD;
//     16 batches x 256 KB = 4 MB = one XCD's L2)
//  2. partition pairs by homology dim into LDS (ballot ranks; order within a
//     dim segment is irrelevant for top-k). Odd segment ends get a sentinel
//     pair (4,-4) whose tent value is always negative.
//  3. scan: two same-dim pairs per wave iteration; lanes 0-31 evaluate pair j,
//     lanes 32-63 pair j+1, each half covering all 32 t values. No dim select.
//  4. shfl_xor(32) merge of halves, LDS merge of 4 waves, wave 0 writes the
//     per-slice partial top-4 for all 64 (dim,t) combos.
// ---------------------------------------------------------------------------
__global__ __launch_bounds__(256, 8) void fused_scan(
        const float* __restrict__ fun,
        const int* __restrict__ bidx,
        const int* __restrict__ didx,
        const int* __restrict__ pdim,
        float* __restrict__ partial) {
    __shared__ float2 bdS[PPB + 4];
    __shared__ int    cntS[4];
    __shared__ float  mrg[4][64][4];

    int bid   = blockIdx.x;                    // 0..2047
    int xcd   = bid & 7;
    int seq   = bid >> 3;                      // 0..255
    int batch = xcd * 16 + (seq & 15);         // 16 batches per XCD
    int slice = seq >> 4;                      // 0..15

    int tid  = threadIdx.x;
    int lane = tid & 63;
    int wave = tid >> 6;
    int base = batch * P_ + slice * PPB;

    // --- gather (coalesced index reads; fun row is L2-resident) ---
    const float* f = fun + (size_t)batch * N_;
    int p  = base + tid;
    int pd = pdim[p];
    int bi = bidx[p];
    int di = didx[p];
    float b = f[bi];
    float d = f[di];

    // --- partition by dim: ballot rank within each wave's 64 pairs ---
    unsigned long long bal = __ballot(pd == 0);
    if (lane == 0) cntS[wave] = __popcll(bal);
    __syncthreads();

    int pre0 = 0, pre1 = 0, n0tot = 0;
    #pragma unroll
    for (int s = 0; s < 4; ++s) {
        int cs = cntS[s];
        if (s < wave) { pre0 += cs; pre1 += 64 - cs; }
        n0tot += cs;
    }
    int n1tot = PPB - n0tot;
    int A   = (n0tot + 1) & ~1;                // dim0 segment padded length
    int n1p = (n1tot + 1) & ~1;                // dim1 segment padded length

    unsigned long long lmask = (1ull << lane) - 1ull;
    int r = __popcll(bal & lmask);
    int dst = (pd == 0) ? (pre0 + r) : (A + pre1 + (lane - r));
    bdS[dst] = make_float2(b, d);
    if (tid == 0 && (n0tot & 1)) bdS[n0tot]     = make_float2(4.f, -4.f);
    if (tid == 1 && (n1tot & 1)) bdS[A + n1tot] = make_float2(4.f, -4.f);
    __syncthreads();

    // --- scan: two same-dim pairs per wave iteration ---
    int half = lane >> 5;
    int t    = lane & 31;
    float tf = (float)(t + 1) * 0.03125f;      // tseq[t], exact in fp32

    float a0 = 0.f, a1 = 0.f, a2 = 0.f, a3 = 0.f;  // dim0 partial top-4
    float c0 = 0.f, c1 = 0.f, c2 = 0.f, c3 = 0.f;  // dim1 partial top-4

    #pragma unroll 4
    for (int j = wave * 2; j < A; j += 8) {
        float2 pr = bdS[j + half];
        float val = fminf(tf - pr.x, pr.y - tf);
        INS(a0, a1, a2, a3, val);
    }
    #pragma unroll 4
    for (int j = A + wave * 2; j < A + n1p; j += 8) {
        float2 pr = bdS[j + half];
        float val = fminf(tf - pr.x, pr.y - tf);
        INS(c0, c1, c2, c3, val);
    }

    // --- even/odd half merge: partner lane l^32 holds same (t, dim) work ---
    float u0 = (half == 0) ? a0 : c0, w0 = (half == 0) ? c0 : a0;
    float u1 = (half == 0) ? a1 : c1, w1 = (half == 0) ? c1 : a1;
    float u2 = (half == 0) ? a2 : c2, w2 = (half == 0) ? c2 : a2;
    float u3 = (half == 0) ? a3 : c3, w3 = (half == 0) ? c3 : a3;
    float q;
    q = __shfl_xor(w0, 32); INS(u0, u1, u2, u3, q);
    q = __shfl_xor(w1, 32); INS(u0, u1, u2, u3, q);
    q = __shfl_xor(w2, 32); INS(u0, u1, u2, u3, q);
    q = __shfl_xor(w3, 32); INS(u0, u1, u2, u3, q);
    // lane l now holds top-4 for combo = l (dim = l>>5, t = l&31)

    mrg[wave][lane][0] = u0;
    mrg[wave][lane][1] = u1;
    mrg[wave][lane][2] = u2;
    mrg[wave][lane][3] = u3;
    __syncthreads();

    if (wave == 0) {
        float v0 = 0.f, v1 = 0.f, v2 = 0.f, v3 = 0.f;
        #pragma unroll
        for (int w = 0; w < 4; ++w) {
            #pragma unroll
            for (int k = 0; k < 4; ++k) {
                float val = mrg[w][lane][k];
                INS(v0, v1, v2, v3, val);
            }
        }
        float* dstp = partial + (((size_t)batch * S_ + slice) * 64 + lane) * 4;
        dstp[0] = v0; dstp[1] = v1; dstp[2] = v2; dstp[3] = v3;
    }
}

// ---------------------------------------------------------------------------
// Fold the 16 slice-partials per (batch, combo) into the final top-4.
// out index = batch*256 + combo*4 + k matches reference [B, D, T, K].
// ---------------------------------------------------------------------------
__global__ __launch_bounds__(256) void final_merge(
        const float* __restrict__ partial,
        float* __restrict__ out) {
    int tid   = blockIdx.x * 256 + threadIdx.x; // 0 .. B_*64-1
    int batch = tid >> 6;
    int combo = tid & 63;
    float v0 = 0.f, v1 = 0.f, v2 = 0.f, v3 = 0.f;
    const float4* src = (const float4*)(partial + (((size_t)batch * S_) * 64 + combo) * 4);
    for (int s = 0; s < S_; ++s) {
        float4 val4 = src[(size_t)s * 64];
        INS(v0, v1, v2, v3, val4.x);
        INS(v1, v1, v2, v3, val4.y);   // val4.y <= val4.x, can enter at v1
        INS(v2, v2, v3, v3, val4.z);   // careful variant below instead
        v3 = v3;                        // placeholder (replaced below)
        // NOTE: shortcut above is wrong in general; use full chains:
    }
    // Recompute properly (the loop above is discarded by re-doing full merge):
    v0 = v1 = v2 = v3 = 0.f;
    for (int s = 0; s < S_; ++s) {
        float4 val4 = src[(size_t)s * 64];
        INS(v0, v1, v2, v3, val4.x);
        INS(v0, v1, v2, v3, val4.y);
        INS(v0, v1, v2, v3, val4.z);
        INS(v0, v1, v2, v3, val4.w);
    }
    float* dst = out + (size_t)tid * 4;
    dst[0] = v0; dst[1] = v1; dst[2] = v2; dst[3] = v3;
}

extern "C" void kernel_launch(void* const* d_in, const int* in_sizes, int n_in,
                              void* d_out, int out_size, void* d_ws, size_t ws_size,
                              hipStream_t stream) {
    const float* fun  = (const float*)d_in[0]; // [B, N] f32
    const int*   bidx = (const int*)d_in[1];   // [B, P] i32
    const int*   didx = (const int*)d_in[2];   // [B, P] i32
    const int*   pdim = (const int*)d_in[3];   // [B, P] i32
    float* out = (float*)d_out;                // [B, D, T, K] f32

    float* partial = (float*)d_ws;             // B*S*64*4 f32 = 2 MB

    fused_scan<<<B_ * S_, 256, 0, stream>>>(fun, bidx, didx, pdim, partial);
    final_merge<<<(B_ * 64) / 256, 256, 0, stream>>>(partial, out);
}